// Round 1
// baseline (119.518 us; speedup 1.0000x reference)
//
#include <hip/hip_runtime.h>

// Problem constants (fixed by setup_inputs):
//   x:  [N=4, C=256, H=56, W=56] fp32
//   w1: [N, heads=1, wc=32, 9,  H, W] fp32   (3x3, pad 1)
//   w2: [N, heads=1, wc=32, 25, H, W] fp32   (5x5, pad 2)
//   out:[N, 2, heads=1, C, H, W] fp32
// out[n,b,c,h,w] = sum_p wB[n, c%32, p, h, w] * x[n, c, h+dh, w+dw]  (zero pad)

#define N_  4
#define C_  256
#define H_  56
#define W_  56
#define HW_ 3136
#define WC_ 32
#define G_  8

__global__ __launch_bounds__(256) void lconv_kernel(
    const float* __restrict__ x,
    const float* __restrict__ w1,
    const float* __restrict__ w2,
    float* __restrict__ out)
{
    const int gid = blockIdx.x * 256 + threadIdx.x;   // over N*WC*HW = 401408
    const int hw = gid % HW_;
    const int nv = gid / HW_;
    const int v  = nv % WC_;
    const int n  = nv / WC_;
    const int h  = hw / W_;
    const int w  = hw % W_;

    // Per-pixel weights: loaded once, reused across all G=8 channel groups.
    float wt1[9];
    float wt2[25];
    {
        const float* p1 = w1 + (size_t)((n * WC_ + v) * 9) * HW_ + hw;
        #pragma unroll
        for (int p = 0; p < 9; ++p) wt1[p] = p1[p * HW_];
        const float* p2 = w2 + (size_t)((n * WC_ + v) * 25) * HW_ + hw;
        #pragma unroll
        for (int p = 0; p < 25; ++p) wt2[p] = p2[p * HW_];
    }

    float* o1 = out + ((size_t)(n * 2 + 0) * C_ + v) * HW_ + hw;
    float* o2 = out + ((size_t)(n * 2 + 1) * C_ + v) * HW_ + hw;

    for (int g = 0; g < G_; ++g) {
        const int c = g * WC_ + v;
        const float* xp = x + ((size_t)n * C_ + c) * HW_;

        // Load the 5x5 patch (zero-padded); the 3x3 window is its interior.
        float patch[25];
        #pragma unroll
        for (int di = 0; di < 5; ++di) {
            const int hh = h + di - 2;
            const bool hok = (hh >= 0) & (hh < H_);
            #pragma unroll
            for (int dj = 0; dj < 5; ++dj) {
                const int ww = w + dj - 2;
                const bool ok = hok & (ww >= 0) & (ww < W_);
                patch[di * 5 + dj] = ok ? xp[hh * W_ + ww] : 0.0f;
            }
        }

        float acc1 = 0.0f;
        float acc2 = 0.0f;
        #pragma unroll
        for (int p = 0; p < 25; ++p) acc2 += wt2[p] * patch[p];
        #pragma unroll
        for (int di = 0; di < 3; ++di)
            #pragma unroll
            for (int dj = 0; dj < 3; ++dj)
                acc1 += wt1[di * 3 + dj] * patch[(di + 1) * 5 + (dj + 1)];

        o1[(size_t)g * WC_ * HW_] = acc1;
        o2[(size_t)g * WC_ * HW_] = acc2;
    }
}

extern "C" void kernel_launch(void* const* d_in, const int* in_sizes, int n_in,
                              void* d_out, int out_size, void* d_ws, size_t ws_size,
                              hipStream_t stream) {
    const float* x  = (const float*)d_in[0];
    const float* w1 = (const float*)d_in[1];
    const float* w2 = (const float*)d_in[2];
    float* out = (float*)d_out;

    const int total = N_ * WC_ * HW_;          // 401408
    dim3 grid(total / 256), block(256);
    hipLaunchKernelGGL(lconv_kernel, grid, block, 0, stream, x, w1, w2, out);
}